// Round 4
// baseline (206.185 us; speedup 1.0000x reference)
//
#include <hip/hip_runtime.h>

typedef _Float16 half8_t __attribute__((ext_vector_type(8)));
typedef _Float16 half4_t __attribute__((ext_vector_type(4)));
typedef float    float4_t __attribute__((ext_vector_type(4)));

#define N_TILES 1024
#define PTS     256
#define IN_F    256
#define OUT_F   256
#define BN      128         // n-half per block
#define NSTEP   8           // K split into 8 x 32
#define OMEGA_C 30.0f

// lgkm-only barrier: ds ops drain, global loads stay in flight.
#define BARRIER() do {                                        \
    asm volatile("s_waitcnt lgkmcnt(0)" ::: "memory");        \
    __builtin_amdgcn_s_barrier();                             \
    asm volatile("" ::: "memory");                            \
  } while (0)

// Weight-stationary: one block = 256x128 output. W^T half-tile lives in LDS
// (65,536 B, XOR-swizzled 16B granules) staged ONCE; main loop has NO barriers,
// NO W traffic, NO A-LDS: x streams global->reg->MFMA.
__global__ __launch_bounds__(512, 4)
void siren_tile_gemm(const float* __restrict__ x,
                     const float* __restrict__ w,
                     const float* __restrict__ bias,
                     const void* __restrict__ idx_raw,
                     float* __restrict__ out) {
  __shared__ _Float16 Wl[BN * 256];  // [n][k] halves; 16B granule g at row n -> g^(n&7)

  const int tid = threadIdx.x;

  // XCD swizzle: both n-halves of a tile adjacent on one XCD (b%8 = hw XCD).
  const int b    = blockIdx.x;
  const int xcd  = b & 7;
  const int rest = b >> 3;             // 0..255
  const int tile = xcd + 8 * (rest >> 1);
  const int nh   = rest & 1;

  // indices dtype self-detect (int64 per reference; int32 if demoted).
  const int hiw  = ((const int*)idx_raw)[2 * (tid & 63) + 1];
  const bool is32 = __any(hiw != 0);
  const int ch = is32 ? ((const int*)idx_raw)[tile]
                      : (int)(((const long long*)idx_raw)[tile]);

  const float* __restrict__ Xg = x + (size_t)tile * (PTS * IN_F);
  const float* __restrict__ Wg = w + (size_t)ch * (IN_F * OUT_F) + nh * BN;
  float*       __restrict__ Og = out + (size_t)tile * (PTS * OUT_F) + nh * BN;

  const int lane = tid & 63;
  const int wid  = tid >> 6;
  const int wm   = (wid >> 1) * 64;   // wave M origin (4 waves in M)
  const int wn   = (wid & 1) * 64;    // wave N origin (2 waves in N)
  const int fr   = lane & 15;
  const int kg   = lane >> 4;

  // ---- issue step-0 x loads FIRST: their HBM latency hides under W staging ----
  float4_t xa[8];
#pragma unroll
  for (int m = 0; m < 4; ++m)
#pragma unroll
    for (int h = 0; h < 2; ++h)
      xa[m * 2 + h] = *(const float4_t*)(Xg + (size_t)(wm + m * 16 + fr) * IN_F + kg * 8 + h * 4);

  // ---- one-time W staging: [K=256][BN=128] f32 -> transposed swizzled LDS f16 ----
  {
    const int s8o = tid >> 8;          // 0..1
    const int kb  = (tid >> 5) & 7;    // k-quad within 32-step
    const int nb  = tid & 31;          // n-quad
#pragma unroll
    for (int sp = 0; sp < 4; ++sp) {
      const int s8 = sp * 2 + s8o;
      const int k0 = s8 * 32 + kb * 4;
      float4_t wv[4];
#pragma unroll
      for (int j = 0; j < 4; ++j)
        wv[j] = *(const float4_t*)(Wg + (size_t)(k0 + j) * OUT_F + nb * 4);
#pragma unroll
      for (int i = 0; i < 4; ++i) {
        const int n = nb * 4 + i;
        const int g = s8 * 4 + (kb >> 1);              // 16B granule index
        half4_t hb = {(_Float16)wv[0][i], (_Float16)wv[1][i],
                      (_Float16)wv[2][i], (_Float16)wv[3][i]};
        *(half4_t*)&Wl[n * 256 + (g ^ (n & 7)) * 8 + (kb & 1) * 4] = hb;
      }
    }
  }
  BARRIER();

  float4_t acc[4][4];
#pragma unroll
  for (int m = 0; m < 4; ++m)
#pragma unroll
    for (int n = 0; n < 4; ++n)
      acc[m][n] = (float4_t){0.f, 0.f, 0.f, 0.f};

  // ---- barrier-free main loop: cvt current, issue next, read W-frags, MFMA ----
#pragma unroll
  for (int s = 0; s < NSTEP; ++s) {
    half8_t af[4];
#pragma unroll
    for (int m = 0; m < 4; ++m) {
      const float4_t lo = xa[m * 2], hi = xa[m * 2 + 1];
      af[m] = (half8_t){(_Float16)lo.x, (_Float16)lo.y, (_Float16)lo.z, (_Float16)lo.w,
                        (_Float16)hi.x, (_Float16)hi.y, (_Float16)hi.z, (_Float16)hi.w};
    }
    if (s + 1 < NSTEP) {
      const int k0 = (s + 1) * 32;
#pragma unroll
      for (int m = 0; m < 4; ++m)
#pragma unroll
        for (int h = 0; h < 2; ++h)
          xa[m * 2 + h] = *(const float4_t*)(Xg + (size_t)(wm + m * 16 + fr) * IN_F + k0 + kg * 8 + h * 4);
    }

    half8_t bf[4];
#pragma unroll
    for (int n = 0; n < 4; ++n) {
      const int r = wn + n * 16 + fr;
      const int g = s * 4 + kg;
      bf[n] = *(const half8_t*)&Wl[r * 256 + (g ^ (r & 7)) * 8];
    }

#pragma unroll
    for (int m = 0; m < 4; ++m)
#pragma unroll
      for (int n = 0; n < 4; ++n)
        acc[m][n] = __builtin_amdgcn_mfma_f32_16x16x32_f16(af[m], bf[n], acc[m][n], 0, 0, 0);
  }

  // ---- epilogue: bias + sin (C/D: col=lane&15, row=(lane>>4)*4+j) ----
  float bv[4];
#pragma unroll
  for (int n = 0; n < 4; ++n) bv[n] = OMEGA_C * bias[nh * BN + wn + n * 16 + fr];

#pragma unroll
  for (int m = 0; m < 4; ++m) {
#pragma unroll
    for (int n = 0; n < 4; ++n) {
#pragma unroll
      for (int j = 0; j < 4; ++j) {
        const int row = wm + m * 16 + kg * 4 + j;
        const int col = wn + n * 16 + fr;
        Og[(size_t)row * OUT_F + col] = __sinf(fmaf(OMEGA_C, acc[m][n][j], bv[n]));
      }
    }
  }
}

extern "C" void kernel_launch(void* const* d_in, const int* in_sizes, int n_in,
                              void* d_out, int out_size, void* d_ws, size_t ws_size,
                              hipStream_t stream) {
  const float* x    = (const float*)d_in[0];
  const float* w    = (const float*)d_in[1];
  const float* bias = (const float*)d_in[2];
  const void*  idx  = d_in[3];
  float*       out  = (float*)d_out;

  siren_tile_gemm<<<N_TILES * 2, 512, 0, stream>>>(x, w, bias, idx, out);
}

// Round 5
// 205.568 us; speedup vs baseline: 1.0030x; 1.0030x over previous
//
#include <hip/hip_runtime.h>

typedef _Float16 half8_t __attribute__((ext_vector_type(8)));
typedef _Float16 half4_t __attribute__((ext_vector_type(4)));
typedef float    float4_t __attribute__((ext_vector_type(4)));

#define N_TILES 1024
#define PTS     256
#define IN_F    256
#define OUT_F   256
#define BM      128
#define BN      128
#define NSTEP   8
#define OMEGA_C 30.0f

// lgkm-only barrier: LDS ops drain, global loads stay in flight.
#define BARRIER() do {                                        \
    asm volatile("s_waitcnt lgkmcnt(0)" ::: "memory");        \
    __builtin_amdgcn_s_barrier();                             \
    asm volatile("" ::: "memory");                            \
  } while (0)

// One block = 128x128 output. W-half staged ONCE to LDS (64KB, XOR-swizzled);
// x streams through a depth-2 register ring; steady loop = ds_read + MFMA only,
// zero barriers, zero W traffic, zero LDS writes.
__global__ __launch_bounds__(512, 4)
void siren_tile_gemm(const float* __restrict__ x,
                     const float* __restrict__ w,
                     const float* __restrict__ bias,
                     const void* __restrict__ idx_raw,
                     float* __restrict__ out) {
  __shared__ _Float16 Wl[BN * 256];   // [n][k], 16B granule g at row n -> g^(n&7)

  const int tid = threadIdx.x;

  // XCD swizzle: 4 sub-blocks of a tile consecutive on one XCD (share x and W via L2).
  const int b    = blockIdx.x;
  const int xcd  = b & 7;
  const int rest = b >> 3;             // 0..511
  const int tile = xcd + 8 * (rest >> 2);
  const int mh   = (rest >> 1) & 1;
  const int nh   = rest & 1;

  // indices dtype self-detect (int64 per reference; int32 if demoted).
  const int hiw   = ((const int*)idx_raw)[2 * (tid & 63) + 1];
  const bool is32 = __any(hiw != 0);
  const int ch = is32 ? ((const int*)idx_raw)[tile]
                      : (int)(((const long long*)idx_raw)[tile]);

  const float* __restrict__ Xg = x + (size_t)tile * (PTS * IN_F) + (size_t)mh * BM * IN_F;
  const float* __restrict__ Wg = w + (size_t)ch * (IN_F * OUT_F) + nh * BN;
  float*       __restrict__ Og = out + (size_t)tile * (PTS * OUT_F) + (size_t)mh * BM * OUT_F + nh * BN;

  const int lane = tid & 63;
  const int wid  = tid >> 6;
  const int wm   = (wid >> 1) * 32;   // wave M origin: 4 groups of 32 rows
  const int wn   = (wid & 1) * 64;    // wave N origin: 2 groups of 64 cols
  const int fr   = lane & 15;
  const int kg   = lane >> 4;

  // ---- prologue A: issue ALL W loads first (oldest in vmcnt queue) ----
  const int s8o = tid >> 8;           // 0..1
  const int kb  = (tid >> 5) & 7;     // k-quad within 32-group
  const int nb  = tid & 31;           // n-quad
  float4_t wv[4][4];
#pragma unroll
  for (int sp = 0; sp < 4; ++sp) {
    const int k0 = (sp * 2 + s8o) * 32 + kb * 4;
#pragma unroll
    for (int j = 0; j < 4; ++j)
      wv[sp][j] = *(const float4_t*)(Wg + (size_t)(k0 + j) * OUT_F + nb * 4);
  }

  // ---- prologue B: x prefetch ring, steps 0..1 (newest -> survive W's waits) ----
  float4_t xf[2][2][2];
#define PF(d, s)                                                                 \
  do {                                                                           \
    _Pragma("unroll")                                                            \
    for (int m_ = 0; m_ < 2; ++m_)                                               \
      _Pragma("unroll")                                                          \
      for (int h_ = 0; h_ < 2; ++h_)                                             \
        xf[d][m_][h_] = *(const float4_t*)(Xg + (size_t)(wm + m_ * 16 + fr) * IN_F \
                                           + (s) * 32 + kg * 8 + h_ * 4);        \
  } while (0)
  PF(0, 0);
  PF(1, 1);

  float bv[4];
#pragma unroll
  for (int n = 0; n < 4; ++n) bv[n] = OMEGA_C * bias[nh * BN + wn + n * 16 + fr];

  // ---- prologue C: W transpose-write (waits drain W only; x stays in flight) ----
#pragma unroll
  for (int sp = 0; sp < 4; ++sp) {
    const int s8 = sp * 2 + s8o;
    const int g  = s8 * 4 + (kb >> 1);
#pragma unroll
    for (int i = 0; i < 4; ++i) {
      const int n = nb * 4 + i;
      half4_t hb = {(_Float16)wv[sp][0][i], (_Float16)wv[sp][1][i],
                    (_Float16)wv[sp][2][i], (_Float16)wv[sp][3][i]};
      *(half4_t*)&Wl[n * 256 + (g ^ (n & 7)) * 8 + (kb & 1) * 4] = hb;
    }
  }
  BARRIER();

  float4_t acc[2][4];
#pragma unroll
  for (int m = 0; m < 2; ++m)
#pragma unroll
    for (int n = 0; n < 4; ++n)
      acc[m][n] = (float4_t){0.f, 0.f, 0.f, 0.f};

  // ---- steady loop: cvt xf[s%2] -> af, refill slot for s+2, ds_read bf, MFMA ----
#pragma unroll
  for (int s = 0; s < NSTEP; ++s) {
    const int d = s & 1;
    half8_t af[2];
#pragma unroll
    for (int m = 0; m < 2; ++m) {
      const float4_t lo = xf[d][m][0], hi = xf[d][m][1];
      af[m] = (half8_t){(_Float16)lo.x, (_Float16)lo.y, (_Float16)lo.z, (_Float16)lo.w,
                        (_Float16)hi.x, (_Float16)hi.y, (_Float16)hi.z, (_Float16)hi.w};
    }
    if (s + 2 < NSTEP) PF(d, s + 2);

    half8_t bf[4];
#pragma unroll
    for (int n = 0; n < 4; ++n) {
      const int r = wn + n * 16 + fr;
      const int g = s * 4 + kg;
      bf[n] = *(const half8_t*)&Wl[r * 256 + (g ^ (r & 7)) * 8];
    }

#pragma unroll
    for (int m = 0; m < 2; ++m)
#pragma unroll
      for (int n = 0; n < 4; ++n)
        acc[m][n] = __builtin_amdgcn_mfma_f32_16x16x32_f16(af[m], bf[n], acc[m][n], 0, 0, 0);
  }

  // ---- epilogue: bias + sin (C/D: col=lane&15, row=(lane>>4)*4+j) ----
#pragma unroll
  for (int m = 0; m < 2; ++m) {
#pragma unroll
    for (int n = 0; n < 4; ++n) {
#pragma unroll
      for (int j = 0; j < 4; ++j) {
        const int row = wm + m * 16 + kg * 4 + j;
        const int col = wn + n * 16 + fr;
        Og[(size_t)row * OUT_F + col] = __sinf(fmaf(OMEGA_C, acc[m][n][j], bv[n]));
      }
    }
  }
}

extern "C" void kernel_launch(void* const* d_in, const int* in_sizes, int n_in,
                              void* d_out, int out_size, void* d_ws, size_t ws_size,
                              hipStream_t stream) {
  const float* x    = (const float*)d_in[0];
  const float* w    = (const float*)d_in[1];
  const float* bias = (const float*)d_in[2];
  const void*  idx  = d_in[3];
  float*       out  = (float*)d_out;

  siren_tile_gemm<<<N_TILES * 4, 512, 0, stream>>>(x, w, bias, idx, out);
}